// Round 8
// baseline (91.417 us; speedup 1.0000x reference)
//
#include <hip/hip_runtime.h>

// CIN (xDeepFM) fused kernel for MI355X (gfx950), round 8.
// f16 datapath (r7) + L0 k-reorder i' = c5*320 + m*8 + j so the xn vector is
// register-resident (chunk c5 constant for 10 steps, double-buffered); only
// scalar xm (m = 4*(s%10)+lhi) read from LDS (4x u16/step, prefetched 1 step
// ahead). L0 fully unrolled for static register indexing. L1: reassociated
// (kh split) with xmv prefetched 1 m ahead. Weight stream layouts as r7.

typedef _Float16 f16x8 __attribute__((ext_vector_type(8)));
typedef float f32x4 __attribute__((ext_vector_type(4)));

#define NB 2
#define NBLK 512
#define THREADS 512
#define K0P 52   // padded steps for prefetch overrun (s 50,51 zero)
#define M1C 40   // L1 compute m-steps (m=39 contributes exactly 0)
#define M1P 42   // L1 padded m-steps

__global__ __launch_bounds__(256) void prep_kernel(
    const float* __restrict__ w0, const float* __restrict__ w1,
    _Float16* __restrict__ w0c, _Float16* __restrict__ w1c) {
  int stride = gridDim.x * blockDim.x;
  int tid = blockIdx.x * blockDim.x + threadIdx.x;
  // w0c: [s<52][w<8][mt<2][l15<16][lhi<4][j<8]; row o=w*32+mt*16+l15,
  // k-index ip = s*32+lhi*8+j; decode c5=ip/320, m=(ip%320)/8, n=c5*8+ip%8.
  const int n0 = K0P * 8192;
  for (int idx = tid; idx < n0; idx += stride) {
    int j = idx & 7, lhi = (idx >> 3) & 3, l15 = (idx >> 5) & 15;
    int mt = (idx >> 9) & 1, w8 = (idx >> 10) & 7, s = idx >> 13;
    int o = w8 * 32 + mt * 16 + l15;
    int ip = s * 32 + lhi * 8 + j;
    float v = 0.f;
    if (ip < 1600) {
      int c5 = ip / 320;
      int m = (ip - c5 * 320) >> 3;
      int n = c5 * 8 + (ip & 7);
      if (m < 39 && n < 39) v = w0[o * 1521 + m * 39 + n];
    }
    w0c[idx] = (_Float16)v;
  }
  // w1c: [m<42][kh<2][rt<4][kf<2][mt<2][l15<16][lhi<4][j<8];
  //      row o=rt*32+mt*16+l15, k = kh*64+kf*32+lhi*8+j (within W1_m).
  const int n1 = M1P * 16384;
  for (int idx = tid; idx < n1; idx += stride) {
    int j = idx & 7, lhi = (idx >> 3) & 3, l15 = (idx >> 5) & 15;
    int mt = (idx >> 9) & 1, kf = (idx >> 10) & 1, rt = (idx >> 11) & 3;
    int kh = (idx >> 13) & 1, m = idx >> 14;
    int o = rt * 32 + mt * 16 + l15;
    int k = kh * 64 + kf * 32 + lhi * 8 + j;
    float v = (m < 39) ? w1[o * 4992 + m * 128 + k] : 0.f;
    w1c[idx] = (_Float16)v;
  }
}

__global__ __launch_bounds__(512, 2) void cin_kernel(
    const float* __restrict__ x,
    const _Float16* __restrict__ w0c, const float* __restrict__ b0,
    const _Float16* __restrict__ w1c, const float* __restrict__ b1,
    float* __restrict__ out) {
  // LDS: 5120 + 17408 + 33280 = 55808 B -> 2 blocks/CU
  __shared__ __align__(16) _Float16 xs[NB * 32 * 40];    // [c=(b,d)][40] (m=39 slot zero)
  __shared__ __align__(16) _Float16 h1[NB * 32 * 136];   // [c][136] h1a (f16)
  __shared__ __align__(16) float red[4 * 32 * 65];       // K-half exchange, row pad 65

  const int t = threadIdx.x;
  const int bb = blockIdx.x * NB;
  const int w = t >> 6;          // wave id 0..7
  const int l15 = t & 15;
  const int lhi = (t >> 4) & 3;
  const int lane_off = ((l15 << 2) | lhi) << 3;  // element offset in 1KB chunk

  int xrow[4];
#pragma unroll
  for (int nt = 0; nt < 4; ++nt) xrow[nt] = (nt * 16 + l15) * 40;

  // ---- load x[b] -> xs transposed [c][m], f16 ----
  for (int idx = t; idx < NB * 39 * 32; idx += THREADS) {
    int b = idx / 1248; int rem = idx - b * 1248;
    int m = rem >> 5; int d = rem & 31;
    xs[(b * 32 + d) * 40 + m] = (_Float16)x[(bb + b) * 1248 + rem];
  }
  if (t < NB * 32) xs[t * 40 + 39] = (_Float16)0.f;  // zero the m=39 pad
  __syncthreads();

  // ================= LAYER 0 (barrier-free, fully unrolled) =================
  f32x4 acc[2][4] = {};
  const _Float16* p0 = w0c + w * 1024 + lane_off;

  f16x8 af[2][2];        // [parity][mt] weight frags, 2-deep
  f16x8 ck[2][4];        // xn chunk frags, dbuf per 10-step group
  _Float16 xmr[2][4];    // xm scalars, 1-step lookahead

  auto loadA0 = [&](int s, int b) {
    const _Float16* p = p0 + s * 8192;
    af[b][0] = *(const f16x8*)(p);
    af[b][1] = *(const f16x8*)(p + 512);
  };
  auto loadCk = [&](int g, int b) {
#pragma unroll
    for (int nt = 0; nt < 4; ++nt)
      ck[b][nt] = *(const f16x8*)&xs[xrow[nt] + g * 8];   // 16B-aligned (80B rows)
  };
  auto xmld = [&](int s, int b) {
    int m = 4 * (s % 10) + lhi;
#pragma unroll
    for (int nt = 0; nt < 4; ++nt) xmr[b][nt] = xs[xrow[nt] + m];
  };

  loadCk(0, 0);
  xmld(0, 0);
  loadA0(0, 0); loadA0(1, 1);
#pragma unroll
  for (int s = 0; s < 50; ++s) {
    const int g = s / 10;
    if (s + 1 < 50) xmld(s + 1, (s + 1) & 1);
    if ((s % 10) == 0 && g + 1 < 5) loadCk(g + 1, (g + 1) & 1);
    f16x8 bz[4];
#pragma unroll
    for (int nt = 0; nt < 4; ++nt) bz[nt] = ck[g & 1][nt] * xmr[s & 1][nt];
#pragma unroll
    for (int mt = 0; mt < 2; ++mt)
#pragma unroll
      for (int nt = 0; nt < 4; ++nt)
        acc[mt][nt] = __builtin_amdgcn_mfma_f32_16x16x32_f16(af[s & 1][mt], bz[nt], acc[mt][nt], 0, 0, 0);
    if (s + 2 <= 51) loadA0(s + 2, s & 1);
  }

  // ---- epilogue 0: bias+relu; o<128 -> h1a LDS; o>=128 -> d-sum -> out[ch 0..127]
  if (w < 4) {
#pragma unroll
    for (int mt = 0; mt < 2; ++mt) {
#pragma unroll
      for (int nt = 0; nt < 4; ++nt) {
        int c = nt * 16 + l15;
        int hbase = c * 136;
#pragma unroll
        for (int r = 0; r < 4; ++r) {
          int o = w * 32 + mt * 16 + lhi * 4 + r;
          float v = fmaxf(acc[mt][nt][r] + b0[o], 0.f);
          h1[hbase + o] = (_Float16)v;
        }
      }
    }
  } else {
#pragma unroll
    for (int mt = 0; mt < 2; ++mt) {
#pragma unroll
      for (int r = 0; r < 4; ++r) {
        int o = w * 32 + mt * 16 + lhi * 4 + r;  // 128..255
        float bias = b0[o];
        float sb0 = 0.f, sb1 = 0.f;
#pragma unroll
        for (int nt = 0; nt < 4; ++nt) {
          float v = fmaxf(acc[mt][nt][r] + bias, 0.f);
          v += __shfl_xor(v, 1); v += __shfl_xor(v, 2);
          v += __shfl_xor(v, 4); v += __shfl_xor(v, 8);
          if (nt < 2) sb0 += v; else sb1 += v;
        }
        if (l15 == 0) {
          out[(bb + 0) * 256 + (o - 128)] = sb0;
          out[(bb + 1) * 256 + (o - 128)] = sb1;
        }
      }
    }
  }
  __syncthreads();  // h1a visible to all waves

  // ============ LAYER 1 (reassociated; 4 row-groups x 2 K-halves) ============
  const int rt = w >> 1;   // row group: rows rt*32 .. rt*32+31
  const int kh = w & 1;    // K half: k in [kh*64, kh*64+64)

  // hf[kf][nt]: persistent B fragments of h for this K-half (32 VGPRs)
  f16x8 hf[2][4];
#pragma unroll
  for (int kf = 0; kf < 2; ++kf)
#pragma unroll
    for (int nt = 0; nt < 4; ++nt)
      hf[kf][nt] = *(const f16x8*)&h1[(nt * 16 + l15) * 136 + (kh * 2 + kf) * 32 + lhi * 8];

  f32x4 acc2[2][4] = {};
  const _Float16* p1 = w1c + (kh * 4 + rt) * 2048 + lane_off;

  float xmv[2][4];
  auto xmvld = [&](int m, int b) {
#pragma unroll
    for (int nt = 0; nt < 4; ++nt) xmv[b][nt] = (float)xs[xrow[nt] + m];
  };
  auto loadA1 = [&](int m, f16x8 (&wf)[2][2]) {
    const _Float16* p = p1 + m * 16384;
    wf[0][0] = *(const f16x8*)(p);
    wf[0][1] = *(const f16x8*)(p + 512);
    wf[1][0] = *(const f16x8*)(p + 1024);
    wf[1][1] = *(const f16x8*)(p + 1536);
  };
  auto computeM = [&](int m, f16x8 (&wf)[2][2], float (&xv)[4]) {
#pragma unroll
    for (int mt = 0; mt < 2; ++mt)
#pragma unroll
      for (int nt = 0; nt < 4; ++nt) {
        f32x4 Y = __builtin_amdgcn_mfma_f32_16x16x32_f16(wf[0][mt], hf[0][nt],
                                                         (f32x4){0.f, 0.f, 0.f, 0.f}, 0, 0, 0);
        Y = __builtin_amdgcn_mfma_f32_16x16x32_f16(wf[1][mt], hf[1][nt], Y, 0, 0, 0);
        acc2[mt][nt] += Y * xv[nt];   // v_pk_fma_f32
      }
  };

  {
    f16x8 wfA[2][2], wfB[2][2];
    loadA1(0, wfA);
    loadA1(1, wfB);
    xmvld(0, 0);
    for (int m = 0; m < M1C; m += 2) {
      xmvld(m + 1, 1);
      computeM(m, wfA, xmv[0]);     loadA1(m + 2, wfA);   // max index 41 < M1P
      if (m + 2 < M1C) xmvld(m + 2, 0);
      computeM(m + 1, wfB, xmv[1]); loadA1(m + 3, wfB);
    }
  }

  // ---- combine K-halves via LDS: kh==1 writes, kh==0 adds ----
  __syncthreads();
  if (kh == 1) {
#pragma unroll
    for (int mt = 0; mt < 2; ++mt)
#pragma unroll
      for (int nt = 0; nt < 4; ++nt)
#pragma unroll
        for (int r = 0; r < 4; ++r) {
          int row = mt * 16 + lhi * 4 + r, c = nt * 16 + l15;
          red[(rt * 32 + row) * 65 + c] = acc2[mt][nt][r];
        }
  }
  __syncthreads();
  if (kh == 0) {
#pragma unroll
    for (int mt = 0; mt < 2; ++mt)
#pragma unroll
      for (int nt = 0; nt < 4; ++nt)
#pragma unroll
        for (int r = 0; r < 4; ++r) {
          int row = mt * 16 + lhi * 4 + r, c = nt * 16 + l15;
          acc2[mt][nt][r] += red[(rt * 32 + row) * 65 + c];
        }

    // ---- epilogue 1: bias+relu, d-sum -> out[ch 128..255]
#pragma unroll
    for (int mt = 0; mt < 2; ++mt) {
#pragma unroll
      for (int r = 0; r < 4; ++r) {
        int o = rt * 32 + mt * 16 + lhi * 4 + r;  // 0..127
        float bias = b1[o];
        float sb0 = 0.f, sb1 = 0.f;
#pragma unroll
        for (int nt = 0; nt < 4; ++nt) {
          float v = fmaxf(acc2[mt][nt][r] + bias, 0.f);
          v += __shfl_xor(v, 1); v += __shfl_xor(v, 2);
          v += __shfl_xor(v, 4); v += __shfl_xor(v, 8);
          if (nt < 2) sb0 += v; else sb1 += v;
        }
        if (l15 == 0) {
          out[(bb + 0) * 256 + 128 + o] = sb0;
          out[(bb + 1) * 256 + 128 + o] = sb1;
        }
      }
    }
  }
}

extern "C" void kernel_launch(void* const* d_in, const int* in_sizes, int n_in,
                              void* d_out, int out_size, void* d_ws, size_t ws_size,
                              hipStream_t stream) {
  const float* x  = (const float*)d_in[0];
  const float* w0 = (const float*)d_in[1];
  const float* b0 = (const float*)d_in[2];
  const float* w1 = (const float*)d_in[3];
  const float* b1 = (const float*)d_in[4];
  float* out = (float*)d_out;

  _Float16* w0c = (_Float16*)d_ws;             // 52*8192  f16 = 851968 B
  _Float16* w1c = w0c + K0P * 8192;            // 42*16384 f16 = 1376256 B

  prep_kernel<<<256, 256, 0, stream>>>(w0, w1, w0c, w1c);
  cin_kernel<<<NBLK, THREADS, 0, stream>>>(x, w0c, b0, w1c, b1, out);
}